// Round 10
// baseline (325.664 us; speedup 1.0000x reference)
//
#include <hip/hip_runtime.h>

// 32 planes of 1024x1024 f32: 5x5 box blur (SAME, zero-pad) -> data-dependent
// threshold (quantile over exact f32 cascade T[k]=T[k-1]-0.0005f) -> binarize
// -> morphological close (5x5 dilate, 5x5 erode) -> f32 0/1 output.
//
// Round 14: pass1 loop-carried chain de-latencied via an 11-slot LDS row
// ring. Round-9 arithmetic: per-iter chain ~2200 cyc == contended global
// load latency inside the carried dependency (load y+3 -> cvt -> cs ->
// next iter); register prefetch is always sunk by the allocator (r2/6/8).
// New: per iter, issue load for row y+8; compute from cs; retire cs +=
// ring[y+3] - ring[y-2] (two ds_read_b128, ~120cyc); then vmcnt-wait ->
// cvt -> ds_write ring[y+8]. Load->use is intra-iteration (nothing to
// sink); ds_write->ds_read has 5 iters of DS-ordered slack. Chain is now
// LDS-only. Ring mapping: slot(row r)=(r-(y0-2))%11; sWr(iy)=(iy+10)%11
// overwrites the slot sub-read at iy-1 (dead). LDS ~54KB -> 3 blocks/CU
// (occupancy down on purpose: trading TLP for 8x shorter chain).
// k_post unchanged (round-12-verified) -- and should now show in top-5.

#define K_STEPS 1024
#define LO_COUNT 28185723u     // ceil(0.84 * 2^25)
#define R_TILE 16              // pass1 rows per block -> 64x32 = 2048 blocks
#define PT_ROWS 16             // post rows per block  -> 64x32 = 2048 blocks

// ws: (unused)[4096] @0 ; hist[1025] @4096 ; kq u8[2^25] @16384 (32MB)
#define OFF_HIST 4096
#define OFF_KQ   16384

typedef float  fx4 __attribute__((ext_vector_type(4)));

struct TTable { float v[K_STEPS]; };
static constexpr TTable make_T() {
    TTable t{};
    float th = 0.5f;                          // TH1_INIT; exact f32 cascade
    for (int k = 0; k < K_STEPS; k++) { t.v[k] = th; th = th - 0.0005f; }
    return t;
}
__device__ constexpr TTable Tc = make_T();

__device__ __forceinline__ uint4 cvt4(float4 f) {
    // x in [0,1) is a multiple of 2^-23 -> x*2^23 is an exact integer in f32
    return make_uint4((unsigned int)(f.x * 8388608.0f),
                      (unsigned int)(f.y * 8388608.0f),
                      (unsigned int)(f.z * 8388608.0f),
                      (unsigned int)(f.w * 8388608.0f));
}

// smallest k with s >= Us[k] (Us non-increasing staircase, ~104857.6 s-units
// per step). Cascade drift <= 1024*2^-25 = 0.061 step; f32 guess arithmetic
// (values < 2^28, fma) <= ~2e-4 step. For s in [U[k],U[k-1]): g in
// (k-1.062, k+0.062]; +0.5 bias -> g' in (k-0.562, k+0.562] -> floor(g') in
// {k-1, k} -> window {lo, lo+1} contains k; indicator sum is exact:
//   lo=k-1: s<Us[k-1] (+1), s>=Us[k] (+0) -> k.   lo=k: both >= -> k.
// s >= U0 (k=0): g' < 0.562 -> lo=0, indicators 0 -> 0. s=0: g'~1000.5 ->
// lo=1000, U[1000]=1 (+1), U[1001]=0 (+0) -> 1001 (= first zero bin).
__device__ __forceinline__ int find_ki(const unsigned int* __restrict__ Us,
                                       float gbias, unsigned int s) {
    float g = fmaf(-(float)s, 9.5367432e-6f, gbias);   // gbias = U0*inv + 0.5
    int lo = (int)g;
    lo = max(0, min(1022, lo));
    unsigned int a0 = Us[lo], a1 = Us[lo + 1];
    return lo + (int)(s < a0) + (int)(s < a1);
}

// Pass 1: 16-row strip per block. Thread t owns cols 4t..4t+3 running sums
// (rows y-2..y+2); the row stream flows through an 11-slot per-thread LDS
// ring (no barriers: each thread touches only its own 16B). Neighbor sums
// from lane t+1 via __shfl_down; edge lanes (wlane==63) keep a private
// neighbor ring (tid 255 wraps to cols 0..3). Outputs cols 4t+2..4t+5
// (tid 255: 1022,1023,0,1). k==0 counted in a register; LDS atomics only
// for k>0. Aligned u32 kq stores via shfl.
__global__ __launch_bounds__(256, 3) void
k_pass1(const float4* __restrict__ x4, const float* __restrict__ bk,
        unsigned int* __restrict__ hist, unsigned short* __restrict__ kq16) {
    __shared__ unsigned int Us[K_STEPS];
    __shared__ unsigned int lh[K_STEPS + 1];
    __shared__ uint4 RA[11][256];               // per-thread 11-row ring
    __shared__ uint4 RB[11][4];                 // edge-lane (per-wave) ring
    int tid = threadIdx.x;
    int p = blockIdx.y, y0 = blockIdx.x * R_TILE;
    int wlane = tid & 63;
    int w = tid >> 6;

    {   // Build U table: U[k] = min{u : u*c > T[k]} exactly.
        // u < 2^27, c = w*2^-23 (24-bit mantissa) -> u*c exact in double.
        double c = (double)bk[0] * (1.0 / 8388608.0);
        #pragma unroll
        for (int i = 0; i < 4; i++) {
            int k = tid + 256 * i;
            double T = (double)Tc.v[k];
            unsigned int u = 0u;
            if (T >= 0.0) {
                u = (unsigned int)(floor(T / c) + 1.0);
                while (u > 0u && (double)(u - 1u) * c > T) u--;
                while (!((double)u * c > T)) u++;
            }
            Us[k] = u;
        }
    }
    for (int i = tid; i < K_STEPS + 1; i += 256) lh[i] = 0u;
    __syncthreads();
    float gbias = fmaf((float)Us[0], 9.5367432e-6f, 0.5f);

    const float4* pf = x4 + (size_t)p * 262144;   // 256 float4 per row
    int tB = (tid < 255) ? tid + 1 : 0;
    const uint4 z4 = make_uint4(0u, 0u, 0u, 0u);
    bool edge = (wlane == 63);

    unsigned int cs0 = 0, cs1 = 0, cs2 = 0, cs3 = 0;
    unsigned int cb0 = 0, cb1 = 0, cb2 = 0, cb3 = 0;  // edge lanes only
    {   // prologue: rows y0-2 .. y0+7 -> slots 0..9 (first 5 into sums).
        #pragma unroll
        for (int i = 0; i < 10; i++) {
            int yy = y0 - 2 + i, yc = min(max(yy, 0), 1023);
            bool v = (unsigned)yy < 1024u;
            float4 ra = pf[yc * 256 + tid];
            uint4 a = v ? cvt4(ra) : z4;
            RA[i][tid] = a;
            if (i < 5) { cs0 += a.x; cs1 += a.y; cs2 += a.z; cs3 += a.w; }
            if (edge) {
                float4 rb = pf[yc * 256 + tB];
                uint4 b = v ? cvt4(rb) : z4;
                RB[i][w] = b;
                if (i < 5) { cb0 += b.x; cb1 += b.y; cb2 += b.z; cb3 += b.w; }
            }
        }
    }

    unsigned int cnt0 = 0;
    int sSub = 0, sAdd = 5, sWr = 10;   // slots of rows y-2, y+3, y+8
    #pragma unroll 4
    for (int iy = 0; iy < R_TILE; iy++) {
        int y = y0 + iy;

        // (1) ISSUE the deep-ahead load (row y+8, clamped address).
        int yn = min(y + 8, 1023);
        float4 Nf = pf[yn * 256 + tid];
        float4 NfB;
        if (edge) NfB = pf[yn * 256 + tB];

        // (2) COMPUTE from current running sums.
        unsigned int nc0 = __shfl_down(cs0, 1);
        unsigned int nc1 = __shfl_down(cs1, 1);
        unsigned int nc2 = __shfl_down(cs2, 1);
        unsigned int nc3 = __shfl_down(cs3, 1);
        if (edge) { nc0 = cb0; nc1 = cb1; nc2 = cb2; nc3 = cb3; }

        unsigned int m123 = cs1 + cs2 + cs3;
        unsigned int h45  = nc0 + nc1;
        unsigned int v0, v1, v2, v3;
        if (tid != 255) {
            v0 = cs0 + m123 + nc0;                // col 4t+2
            v1 = m123 + h45;                      // col 4t+3
            v2 = cs2 + cs3 + h45 + nc2;           // col 4t+4
            v3 = cs3 + h45 + nc2 + nc3;           // col 4t+5
        } else {
            v0 = cs0 + m123;                      // col 1022 (cols 1020..1023)
            v1 = m123;                            // col 1023 (cols 1021..1023)
            v2 = h45 + nc2;                       // col 0    (cols 0..2)
            v3 = h45 + nc2 + nc3;                 // col 1    (cols 0..3)
        }

        int k0 = find_ki(Us, gbias, v0);
        int k1 = find_ki(Us, gbias, v1);
        int k2 = find_ki(Us, gbias, v2);
        int k3 = find_ki(Us, gbias, v3);
        cnt0 += (unsigned)(k0 == 0) + (unsigned)(k1 == 0)
              + (unsigned)(k2 == 0) + (unsigned)(k3 == 0);
        if (k0 > 0) atomicAdd(&lh[k0], 1u);
        if (k1 > 0) atomicAdd(&lh[k1], 1u);
        if (k2 > 0) atomicAdd(&lh[k2], 1u);
        if (k3 > 0) atomicAdd(&lh[k3], 1u);

        // pack + aligned coalesced store. Word w = cols 4w..4w+3.
        // word(t+1) = pb(t) | pa(t+1)<<16 (wlane<63 via shfl); words 64w:
        // low half = pb of wlane==63 (u16 at 2t+2; tid 255 -> u16 0),
        // high half = pa of wlane==0 (u16 at 2t+1).
        unsigned int pa = (unsigned)min(k0, 255) | ((unsigned)min(k1, 255) << 8);
        unsigned int pb = (unsigned)min(k2, 255) | ((unsigned)min(k3, 255) << 8);
        unsigned int paN = __shfl_down(pa, 1);
        size_t rb = ((size_t)p * 1024 + (size_t)y) * 512;   // u16 units
        if (wlane < 63) {
            ((unsigned int*)(kq16 + rb))[tid + 1] = pb | (paN << 16);
        } else {
            kq16[rb + ((tid < 255) ? (unsigned)(2 * tid + 2) : 0u)] =
                (unsigned short)pb;
        }
        if (wlane == 0) kq16[rb + 2 * tid + 1] = (unsigned short)pa;

        // (3) RETIRE from the LDS ring: cs += row(y+3) - row(y-2).
        {
            uint4 na = RA[sAdd][tid];
            uint4 oa = RA[sSub][tid];
            cs0 += na.x - oa.x; cs1 += na.y - oa.y;
            cs2 += na.z - oa.z; cs3 += na.w - oa.w;
            if (edge) {
                uint4 nb = RB[sAdd][w];
                uint4 ob = RB[sSub][w];
                cb0 += nb.x - ob.x; cb1 += nb.y - ob.y;
                cb2 += nb.z - ob.z; cb3 += nb.w - ob.w;
            }
        }

        // (4) STAGE the loaded row into the ring (vmcnt wait lands here,
        // at the END of the iteration -- not on the carried chain).
        {
            bool vw = (unsigned)(y + 8) < 1024u;
            RA[sWr][tid] = vw ? cvt4(Nf) : z4;
            if (edge) RB[sWr][w] = vw ? cvt4(NfB) : z4;
        }

        sSub++; if (sSub == 11) sSub = 0;
        sAdd++; if (sAdd == 11) sAdd = 0;
        sWr++;  if (sWr == 11)  sWr = 0;
    }

    #pragma unroll
    for (int d = 32; d > 0; d >>= 1) cnt0 += __shfl_down(cnt0, d);
    if ((tid & 63) == 0 && cnt0) atomicAdd(&lh[0], cnt0);
    __syncthreads();
    for (int i = tid; i < K_STEPS + 1; i += 256) {
        unsigned int c = lh[i];
        if (c) atomicAdd(&hist[i], c);
    }
}

// Fused post: in-block solve -> binarize (k<=ks) -> dilate -> erode -> f32
// unpack. 16-row tile per block, bit-packed intermediates in LDS. kq loads
// hoisted ABOVE the solve so hist-read latency and kq-read latency overlap.
// Out-of-plane rows are masked to 0 AFTER the byte compares (a zero byte
// binarizes to 1 — round-7 bug).
// Loop 2 of the reference (frac > 0.86) cannot trigger: it needs a single
// 0.0005-wide bin holding >= 671089 px; max possible ~115k.
__global__ __launch_bounds__(256, 6) void
k_post(const unsigned char* __restrict__ kqb, const unsigned int* __restrict__ hist,
       float* __restrict__ out) {
    __shared__ unsigned long long Tt[24 * 16];  // thr rows y0-4 .. y0+19
    __shared__ unsigned long long Vv[20 * 16];  // vertical OR, rows y0-2 .. y0+17
    __shared__ unsigned long long Dd[20 * 16];  // dilated,     rows y0-2 .. y0+17
    __shared__ unsigned long long Ww[16 * 16];  // vertical AND, rows y0 .. y0+15
    __shared__ unsigned long long Ff[16 * 16];  // closed bits
    __shared__ int ksS;

    int tid = threadIdx.x;
    int p = blockIdx.y, y0 = blockIdx.x * PT_ROWS;

    // Phase -1: ISSUE all six kq chunk loads (independent of ks).
    const unsigned char* kp = kqb + (size_t)p * 1048576;
    uint4 q0, q1, q2, q3, q4, q5;
    {
        const uint4 zq = make_uint4(0u, 0u, 0u, 0u);
        #pragma unroll
        for (int i = 0; i < 6; i++) {
            int ch = tid + 256 * i;         // 0..1535
            int r = ch >> 6, cc = ch & 63;
            int pr = y0 - 4 + r;
            uint4 q = zq;
            if ((unsigned)pr < 1024u)
                q = ((const uint4*)(kp + (size_t)pr * 1024))[cc];
            if (i == 0) q0 = q; else if (i == 1) q1 = q;
            else if (i == 2) q2 = q; else if (i == 3) q3 = q;
            else if (i == 4) q4 = q; else q5 = q;
        }
    }

    // Phase 0: solve (wave 0 only) — runs under the kq load latency.
    if (tid < 64) {
        int lane = tid;
        unsigned int h[16], s = 0;
        #pragma unroll
        for (int i = 0; i < 16; i++) { h[i] = hist[lane * 16 + i]; s += h[i]; }
        unsigned int inc = s;
        #pragma unroll
        for (int d = 1; d < 64; d <<= 1) {
            unsigned int t = __shfl_up(inc, d);
            if (lane >= d) inc += t;
        }
        unsigned int excl = inc - s;
        bool cross = (excl < LO_COUNT) && (excl + s >= LO_COUNT);
        unsigned long long m = __ballot(cross);
        if (m) {
            int cl = __ffsll((long long)m) - 1;
            if (lane == cl) {
                unsigned int c = excl; int ks = K_STEPS - 1;
                for (int i = 0; i < 16; i++) { c += h[i]; if (c >= LO_COUNT) { ks = lane * 16 + i; break; } }
                ksS = ks;
            }
        } else if (lane == 0) ksS = K_STEPS - 1;
    }
    __syncthreads();
    int ks = ksS;

    // Phase 1: binarize the held chunks -> 16-bit masks -> LDS.
    // Out-of-plane rows masked to 0 AFTER the compares.
    unsigned short* Tt16 = (unsigned short*)Tt;
    #pragma unroll
    for (int i = 0; i < 6; i++) {
        uint4 q = (i == 0) ? q0 : (i == 1) ? q1 : (i == 2) ? q2
                : (i == 3) ? q3 : (i == 4) ? q4 : q5;
        int ch = tid + 256 * i;
        int r = ch >> 6;
        int pr = y0 - 4 + r;
        unsigned int m = 0u;
        unsigned int wv;
        wv = q.x;
        m |= (unsigned)((wv & 0xffu) <= (unsigned)ks)
           | ((unsigned)(((wv >> 8) & 0xffu) <= (unsigned)ks) << 1)
           | ((unsigned)(((wv >> 16) & 0xffu) <= (unsigned)ks) << 2)
           | ((unsigned)((wv >> 24) <= (unsigned)ks) << 3);
        wv = q.y;
        m |= ((unsigned)((wv & 0xffu) <= (unsigned)ks) << 4)
           | ((unsigned)(((wv >> 8) & 0xffu) <= (unsigned)ks) << 5)
           | ((unsigned)(((wv >> 16) & 0xffu) <= (unsigned)ks) << 6)
           | ((unsigned)((wv >> 24) <= (unsigned)ks) << 7);
        wv = q.z;
        m |= ((unsigned)((wv & 0xffu) <= (unsigned)ks) << 8)
           | ((unsigned)(((wv >> 8) & 0xffu) <= (unsigned)ks) << 9)
           | ((unsigned)(((wv >> 16) & 0xffu) <= (unsigned)ks) << 10)
           | ((unsigned)((wv >> 24) <= (unsigned)ks) << 11);
        wv = q.w;
        m |= ((unsigned)((wv & 0xffu) <= (unsigned)ks) << 12)
           | ((unsigned)(((wv >> 8) & 0xffu) <= (unsigned)ks) << 13)
           | ((unsigned)(((wv >> 16) & 0xffu) <= (unsigned)ks) << 14)
           | ((unsigned)((wv >> 24) <= (unsigned)ks) << 15);
        if ((unsigned)pr >= 1024u) m = 0u;     // halo rows are OUTSIDE: thr=0
        Tt16[ch] = (unsigned short)m;
    }
    __syncthreads();

    // Phase 2: vertical OR of 5 thr rows (20 rows x 16 words = 320)
    for (int i = tid; i < 320; i += 256) {
        int vr = i >> 4, wc = i & 15;
        int b = vr * 16 + wc;
        Vv[i] = Tt[b] | Tt[b + 16] | Tt[b + 32] | Tt[b + 48] | Tt[b + 64];
    }
    __syncthreads();

    // Phase 3: horizontal dilate; rows outside the plane forced to all-ones
    // (erode identity — erosion ignores out-of-image rows).
    for (int i = tid; i < 320; i += 256) {
        int vr = i >> 4, wc = i & 15;
        int pr = y0 - 2 + vr;
        if ((unsigned)pr >= 1024u) { Dd[i] = ~0ull; continue; }
        unsigned long long Vc = Vv[i];
        unsigned long long Vl = (wc > 0)  ? Vv[i - 1] : 0ull;
        unsigned long long Vr = (wc < 15) ? Vv[i + 1] : 0ull;
        Dd[i] = Vc
            | (Vc << 1) | (Vl >> 63)
            | (Vc << 2) | (Vl >> 62)
            | (Vc >> 1) | (Vr << 63)
            | (Vc >> 2) | (Vr << 62);
    }
    __syncthreads();

    // Phase 4: vertical AND of 5 dilated rows (16 x 16 = 256)
    {
        int wr = tid >> 4, wc = tid & 15;
        int b = wr * 16 + wc;
        Ww[tid] = Dd[b] & Dd[b + 16] & Dd[b + 32] & Dd[b + 48] & Dd[b + 64];
    }
    __syncthreads();

    // Phase 5: horizontal erode (outside cols = 1)
    {
        int wc = tid & 15;
        unsigned long long Wc = Ww[tid];
        unsigned long long Wl = (wc > 0)  ? Ww[tid - 1] : ~0ull;
        unsigned long long Wr = (wc < 15) ? Ww[tid + 1] : ~0ull;
        Ff[tid] = Wc
            & ((Wc << 1) | (Wl >> 63))
            & ((Wc << 2) | (Wl >> 62))
            & ((Wc >> 1) | (Wr << 63))
            & ((Wc >> 2) | (Wr << 62));
    }
    __syncthreads();

    // Phase 6: unpack to f32, nontemporal coalesced 16B stores
    for (int i = 0; i < PT_ROWS; i++) {
        unsigned long long wd = Ff[i * 16 + (tid >> 4)];
        int sh = (tid & 15) * 4;
        fx4 f;
        f.x = (float)((wd >> sh) & 1ull);
        f.y = (float)((wd >> (sh + 1)) & 1ull);
        f.z = (float)((wd >> (sh + 2)) & 1ull);
        f.w = (float)((wd >> (sh + 3)) & 1ull);
        fx4* dst = (fx4*)(out + (size_t)p * 1048576 + (size_t)(y0 + i) * 1024) + tid;
        __builtin_nontemporal_store(f, dst);
    }
}

extern "C" void kernel_launch(void* const* d_in, const int* in_sizes, int n_in,
                              void* d_out, int out_size, void* d_ws, size_t ws_size,
                              hipStream_t stream) {
    const float4* x4 = (const float4*)d_in[0];
    const float*  bk = (const float*)d_in[1];
    float* out = (float*)d_out;

    char* ws = (char*)d_ws;
    unsigned int*   hist = (unsigned int*)(ws + OFF_HIST);
    unsigned short* kq16 = (unsigned short*)(ws + OFF_KQ);
    const unsigned char* kqb = (const unsigned char*)(ws + OFF_KQ);

    (void)hipMemsetAsync(hist, 0, (K_STEPS + 1) * sizeof(unsigned int), stream);

    dim3 g1(1024 / R_TILE, 32);
    k_pass1<<<g1, 256, 0, stream>>>(x4, bk, hist, kq16);

    dim3 g2(1024 / PT_ROWS, 32);
    k_post<<<g2, 256, 0, stream>>>(kqb, hist, out);
}

// Round 11
// 276.484 us; speedup vs baseline: 1.1779x; 1.1779x over previous
//
#include <hip/hip_runtime.h>

// 32 planes of 1024x1024 f32: 5x5 box blur (SAME, zero-pad) -> data-dependent
// threshold (quantile over exact f32 cascade T[k]=T[k-1]-0.0005f) -> binarize
// -> morphological close (5x5 dilate, 5x5 erode) -> f32 0/1 output.
//
// Round 15: revert to the empirical best of the session and fuse k_post
// barriers.
//  - pass1: round-3 structure exactly (session best, 88us): 8 running
//    column sums from two full streams, 2-deep N/O prefetch, (256,4).
//    Fancier variants (shuffle-neighbor r8, LDS history r9, deep ring r10)
//    all measured SLOWER: allocator sinking / occupancy collapse.
//    Kept orthogonal wins: constexpr T + in-block Us (no k_init),
//    2-read find_ki, aligned u32 kq stores via shfl.
//  - k_post: round-6 version (loads in-phase, plain (256), nontemporal
//    stores; the r8/9 hoist+bound cost ~14us by cross-round A/B) + fusion
//    of phases 2+3 and 4+5 using 64-bit shuffles for horizontal neighbor
//    words (row's 16 words live in 16 consecutive lanes; wc edges handled;
//    both loop trips are whole-wave so exec masks are full). Drops 2 of 6
//    barriers + the Vv/Ww LDS round-trips.

#define K_STEPS 1024
#define LO_COUNT 28185723u     // ceil(0.84 * 2^25)
#define R_TILE 16              // pass1 rows per block -> 64x32 = 2048 blocks
#define PT_ROWS 16             // post rows per block  -> 64x32 = 2048 blocks

// ws: (unused)[4096] @0 ; hist[1025] @4096 ; kq u8[2^25] @16384 (32MB)
#define OFF_HIST 4096
#define OFF_KQ   16384

typedef float  fx4 __attribute__((ext_vector_type(4)));

struct TTable { float v[K_STEPS]; };
static constexpr TTable make_T() {
    TTable t{};
    float th = 0.5f;                          // TH1_INIT; exact f32 cascade
    for (int k = 0; k < K_STEPS; k++) { t.v[k] = th; th = th - 0.0005f; }
    return t;
}
__device__ constexpr TTable Tc = make_T();

__device__ __forceinline__ uint4 cvt4(float4 f) {
    // x in [0,1) is a multiple of 2^-23 -> x*2^23 is an exact integer in f32
    return make_uint4((unsigned int)(f.x * 8388608.0f),
                      (unsigned int)(f.y * 8388608.0f),
                      (unsigned int)(f.z * 8388608.0f),
                      (unsigned int)(f.w * 8388608.0f));
}

// smallest k with s >= Us[k] (Us non-increasing staircase, ~104857.6 s-units
// per step). Cascade drift <= 1024*2^-25 = 0.061 step; f32 guess arithmetic
// (values < 2^28, fma) <= ~2e-4 step. For s in [U[k],U[k-1]): g in
// (k-1.062, k+0.062]; +0.5 bias -> g' in (k-0.562, k+0.562] -> floor(g') in
// {k-1, k} -> window {lo, lo+1} contains k; indicator sum is exact:
//   lo=k-1: s<Us[k-1] (+1), s>=Us[k] (+0) -> k.   lo=k: both >= -> k.
// s >= U0 (k=0): g' < 0.562 -> lo=0, indicators 0 -> 0. s=0: g'~1000.5 ->
// lo=1000, U[1000]=1 (+1), U[1001]=0 (+0) -> 1001 (= first zero bin).
__device__ __forceinline__ int find_ki(const unsigned int* __restrict__ Us,
                                       float gbias, unsigned int s) {
    float g = fmaf(-(float)s, 9.5367432e-6f, gbias);   // gbias = U0*inv + 0.5
    int lo = (int)g;
    lo = max(0, min(1022, lo));
    unsigned int a0 = Us[lo], a1 = Us[lo + 1];
    return lo + (int)(s < a0) + (int)(s < a1);
}

// Pass 1 (round-3 structure): 16-row strip per block. Thread t loads f4[t]
// (cols 4t..4t+3) and f4[t+1] (thread 255: f4[0]); 8 running column sums;
// outputs cols 4t+2..4t+5 (tid 255: 1022,1023,0,1). Two prefetch streams
// (incoming y+3, departing y-2), both issued 2 rows ahead. k==0 (~50% of
// px) counted in a register; LDS atomics only for k>0. Aligned u32 kq
// stores via shfl.
__global__ __launch_bounds__(256, 4) void
k_pass1(const float4* __restrict__ x4, const float* __restrict__ bk,
        unsigned int* __restrict__ hist, unsigned short* __restrict__ kq16) {
    __shared__ unsigned int Us[K_STEPS];
    __shared__ unsigned int lh[K_STEPS + 1];
    int tid = threadIdx.x;
    int p = blockIdx.y, y0 = blockIdx.x * R_TILE;

    {   // Build U table: U[k] = min{u : u*c > T[k]} exactly.
        // u < 2^27, c = w*2^-23 (24-bit mantissa) -> u*c exact in double.
        double c = (double)bk[0] * (1.0 / 8388608.0);
        #pragma unroll
        for (int i = 0; i < 4; i++) {
            int k = tid + 256 * i;
            double T = (double)Tc.v[k];
            unsigned int u = 0u;
            if (T >= 0.0) {
                u = (unsigned int)(floor(T / c) + 1.0);
                while (u > 0u && (double)(u - 1u) * c > T) u--;
                while (!((double)u * c > T)) u++;
            }
            Us[k] = u;
        }
    }
    for (int i = tid; i < K_STEPS + 1; i += 256) lh[i] = 0u;
    __syncthreads();
    float gbias = fmaf((float)Us[0], 9.5367432e-6f, 0.5f);

    const float4* pf = x4 + (size_t)p * 262144;   // 256 float4 per row
    int tB = (tid < 255) ? tid + 1 : 0;
    const uint4 z4 = make_uint4(0u, 0u, 0u, 0u);

    unsigned int cs0 = 0, cs1 = 0, cs2 = 0, cs3 = 0,
                 cs4 = 0, cs5 = 0, cs6 = 0, cs7 = 0;
    {   // prologue: rows y0-2 .. y0+2 into the running sums
        float4 ra[5], rb[5];
        #pragma unroll
        for (int i = 0; i < 5; i++) {
            int yy = y0 - 2 + i, yc = min(max(yy, 0), 1023);
            ra[i] = pf[yc * 256 + tid];
            rb[i] = pf[yc * 256 + tB];
        }
        #pragma unroll
        for (int i = 0; i < 5; i++) {
            bool v = (unsigned)(y0 - 2 + i) < 1024u;
            uint4 a = v ? cvt4(ra[i]) : z4;
            uint4 b = v ? cvt4(rb[i]) : z4;
            cs0 += a.x; cs1 += a.y; cs2 += a.z; cs3 += a.w;
            cs4 += b.x; cs5 += b.y; cs6 += b.z; cs7 += b.w;
        }
    }
    // prefetch slots: N = incoming rows (y+3), O = departing rows (y-2)
    float4 N0a, N0b, N1a, N1b, O0a, O0b, O1a, O1b;
    {
        int yn0 = min(y0 + 3, 1023), yn1 = min(y0 + 4, 1023);
        int yo0 = max(y0 - 2, 0),    yo1 = max(y0 - 1, 0);
        N0a = pf[yn0 * 256 + tid]; N0b = pf[yn0 * 256 + tB];
        N1a = pf[yn1 * 256 + tid]; N1b = pf[yn1 * 256 + tB];
        O0a = pf[yo0 * 256 + tid]; O0b = pf[yo0 * 256 + tB];
        O1a = pf[yo1 * 256 + tid]; O1b = pf[yo1 * 256 + tB];
    }

    unsigned int cnt0 = 0;
    int wlane = tid & 63;
    #pragma unroll 4
    for (int iy = 0; iy < R_TILE; iy++) {
        int y = y0 + iy;

        unsigned int m123 = cs1 + cs2 + cs3;
        unsigned int h45  = cs4 + cs5;
        unsigned int v0, v1, v2, v3;
        if (tid != 255) {
            v0 = cs0 + m123 + cs4;                // col 4t+2
            v1 = m123 + h45;                      // col 4t+3
            v2 = cs2 + cs3 + h45 + cs6;           // col 4t+4
            v3 = cs3 + h45 + cs6 + cs7;           // col 4t+5
        } else {
            v0 = cs0 + m123;                      // col 1022 (cols 1020..1023)
            v1 = m123;                            // col 1023 (cols 1021..1023)
            v2 = h45 + cs6;                       // col 0    (cols 0..2)
            v3 = h45 + cs6 + cs7;                 // col 1    (cols 0..3)
        }

        int k0 = find_ki(Us, gbias, v0);
        int k1 = find_ki(Us, gbias, v1);
        int k2 = find_ki(Us, gbias, v2);
        int k3 = find_ki(Us, gbias, v3);
        cnt0 += (unsigned)(k0 == 0) + (unsigned)(k1 == 0)
              + (unsigned)(k2 == 0) + (unsigned)(k3 == 0);
        if (k0 > 0) atomicAdd(&lh[k0], 1u);
        if (k1 > 0) atomicAdd(&lh[k1], 1u);
        if (k2 > 0) atomicAdd(&lh[k2], 1u);
        if (k3 > 0) atomicAdd(&lh[k3], 1u);

        // pack + aligned coalesced store. Word w = cols 4w..4w+3.
        // word(t+1) = pb(t) | pa(t+1)<<16 (wlane<63 via shfl); words 64w:
        // low half = pb of wlane==63 (u16 at 2t+2; tid 255 -> u16 0),
        // high half = pa of wlane==0 (u16 at 2t+1).
        unsigned int pa = (unsigned)min(k0, 255) | ((unsigned)min(k1, 255) << 8);
        unsigned int pb = (unsigned)min(k2, 255) | ((unsigned)min(k3, 255) << 8);
        unsigned int paN = __shfl_down(pa, 1);
        size_t rb = ((size_t)p * 1024 + (size_t)y) * 512;   // u16 units
        if (wlane < 63) {
            ((unsigned int*)(kq16 + rb))[tid + 1] = pb | (paN << 16);
        } else {
            kq16[rb + ((tid < 255) ? (unsigned)(2 * tid + 2) : 0u)] =
                (unsigned short)pb;
        }
        if (wlane == 0) kq16[rb + 2 * tid + 1] = (unsigned short)pa;

        // cs update: += row(y+3) [N0], -= row(y-2) [O0] (exact u32)
        {
            bool vn = (unsigned)(y + 3) < 1024u;
            bool vo = (y - 2) >= 0;
            uint4 na = vn ? cvt4(N0a) : z4;
            uint4 nb = vn ? cvt4(N0b) : z4;
            uint4 oa = vo ? cvt4(O0a) : z4;
            uint4 ob = vo ? cvt4(O0b) : z4;
            cs0 += na.x - oa.x; cs1 += na.y - oa.y;
            cs2 += na.z - oa.z; cs3 += na.w - oa.w;
            cs4 += nb.x - ob.x; cs5 += nb.y - ob.y;
            cs6 += nb.z - ob.z; cs7 += nb.w - ob.w;
        }
        // rotate prefetch, refill 2 iterations ahead:
        // iter iy+2 adds row y+5, subtracts row y (always in-range).
        N0a = N1a; N0b = N1b; O0a = O1a; O0b = O1b;
        {
            int yn = min(y + 5, 1023);
            N1a = pf[yn * 256 + tid]; N1b = pf[yn * 256 + tB];
            O1a = pf[y * 256 + tid];  O1b = pf[y * 256 + tB];
        }
    }

    #pragma unroll
    for (int d = 32; d > 0; d >>= 1) cnt0 += __shfl_down(cnt0, d);
    if ((tid & 63) == 0 && cnt0) atomicAdd(&lh[0], cnt0);
    __syncthreads();
    for (int i = tid; i < K_STEPS + 1; i += 256) {
        unsigned int c = lh[i];
        if (c) atomicAdd(&hist[i], c);
    }
}

// Fused post: in-block solve -> binarize (k<=ks) -> dilate -> erode -> f32
// unpack. 16-row tile per block, bit-packed intermediates in LDS.
// Horizontal neighbor words via 64-bit shuffles (a row's 16 words are in 16
// consecutive lanes; wc==0/15 edges handled; both trips of the 320-item
// loop cover whole waves). 4 barriers total.
// Loop 2 of the reference (frac > 0.86) cannot trigger: it needs a single
// 0.0005-wide bin holding >= 671089 px; max possible ~115k.
__global__ __launch_bounds__(256) void
k_post(const unsigned char* __restrict__ kqb, const unsigned int* __restrict__ hist,
       float* __restrict__ out) {
    __shared__ unsigned long long Tt[24 * 16];  // thr rows y0-4 .. y0+19
    __shared__ unsigned long long Dd[20 * 16];  // dilated, rows y0-2 .. y0+17
    __shared__ unsigned long long Ff[16 * 16];  // closed bits
    __shared__ int ksS;

    int tid = threadIdx.x;
    int p = blockIdx.y, y0 = blockIdx.x * PT_ROWS;

    // Phase 0: solve (wave 0 only), redundant per block.
    if (tid < 64) {
        int lane = tid;
        unsigned int h[16], s = 0;
        #pragma unroll
        for (int i = 0; i < 16; i++) { h[i] = hist[lane * 16 + i]; s += h[i]; }
        unsigned int inc = s;
        #pragma unroll
        for (int d = 1; d < 64; d <<= 1) {
            unsigned int t = __shfl_up(inc, d);
            if (lane >= d) inc += t;
        }
        unsigned int excl = inc - s;
        bool cross = (excl < LO_COUNT) && (excl + s >= LO_COUNT);
        unsigned long long m = __ballot(cross);
        if (m) {
            int cl = __ffsll((long long)m) - 1;
            if (lane == cl) {
                unsigned int c = excl; int ks = K_STEPS - 1;
                for (int i = 0; i < 16; i++) { c += h[i]; if (c >= LO_COUNT) { ks = lane * 16 + i; break; } }
                ksS = ks;
            }
        } else if (lane == 0) ksS = K_STEPS - 1;
    }
    __syncthreads();
    int ks = ksS;

    // Phase 1: threshold bits. Each thread: 6 x (uint4 load of 16 kq bytes
    // -> 16-bit mask -> u16 LDS write). Out-of-plane rows stay 0.
    const unsigned char* kp = kqb + (size_t)p * 1048576;
    unsigned short* Tt16 = (unsigned short*)Tt;
    #pragma unroll
    for (int i = 0; i < 6; i++) {
        int ch = tid + 256 * i;             // 0..1535
        int r = ch >> 6, cc = ch & 63;
        int pr = y0 - 4 + r;
        unsigned int m = 0u;
        if ((unsigned)pr < 1024u) {
            uint4 q = ((const uint4*)(kp + (size_t)pr * 1024))[cc];
            unsigned int wv;
            wv = q.x;
            m |= (unsigned)((wv & 0xffu) <= (unsigned)ks)
               | ((unsigned)(((wv >> 8) & 0xffu) <= (unsigned)ks) << 1)
               | ((unsigned)(((wv >> 16) & 0xffu) <= (unsigned)ks) << 2)
               | ((unsigned)((wv >> 24) <= (unsigned)ks) << 3);
            wv = q.y;
            m |= ((unsigned)((wv & 0xffu) <= (unsigned)ks) << 4)
               | ((unsigned)(((wv >> 8) & 0xffu) <= (unsigned)ks) << 5)
               | ((unsigned)(((wv >> 16) & 0xffu) <= (unsigned)ks) << 6)
               | ((unsigned)((wv >> 24) <= (unsigned)ks) << 7);
            wv = q.z;
            m |= ((unsigned)((wv & 0xffu) <= (unsigned)ks) << 8)
               | ((unsigned)(((wv >> 8) & 0xffu) <= (unsigned)ks) << 9)
               | ((unsigned)(((wv >> 16) & 0xffu) <= (unsigned)ks) << 10)
               | ((unsigned)((wv >> 24) <= (unsigned)ks) << 11);
            wv = q.w;
            m |= ((unsigned)((wv & 0xffu) <= (unsigned)ks) << 12)
               | ((unsigned)(((wv >> 8) & 0xffu) <= (unsigned)ks) << 13)
               | ((unsigned)(((wv >> 16) & 0xffu) <= (unsigned)ks) << 14)
               | ((unsigned)((wv >> 24) <= (unsigned)ks) << 15);
        }
        Tt16[ch] = (unsigned short)m;
    }
    __syncthreads();

    // Phase 2+3 fused: vertical OR of 5 thr rows, then horizontal dilate
    // with neighbor words via shuffle. Rows outside plane -> all-ones
    // (erode identity). 20 rows x 16 words; trip 1 = waves 0-3 full,
    // trip 2 = wave 0 full (256 % 16 == 0: rows never straddle trips).
    for (int i = tid; i < 320; i += 256) {
        int vr = i >> 4, wc = i & 15;
        int b = vr * 16 + wc;
        unsigned long long Vc = Tt[b] | Tt[b + 16] | Tt[b + 32]
                              | Tt[b + 48] | Tt[b + 64];
        unsigned long long Vl = __shfl_up(Vc, 1);
        unsigned long long Vr = __shfl_down(Vc, 1);
        if (wc == 0)  Vl = 0ull;
        if (wc == 15) Vr = 0ull;
        int pr = y0 - 2 + vr;
        unsigned long long d;
        if ((unsigned)pr >= 1024u) {
            d = ~0ull;
        } else {
            d = Vc
              | (Vc << 1) | (Vl >> 63)
              | (Vc << 2) | (Vl >> 62)
              | (Vc >> 1) | (Vr << 63)
              | (Vc >> 2) | (Vr << 62);
        }
        Dd[i] = d;
    }
    __syncthreads();

    // Phase 4+5 fused: vertical AND of 5 dilated rows, then horizontal
    // erode with neighbor words via shuffle (outside cols = 1).
    {
        int wr = tid >> 4, wc = tid & 15;
        int b = wr * 16 + wc;
        unsigned long long Wc = Dd[b] & Dd[b + 16] & Dd[b + 32]
                              & Dd[b + 48] & Dd[b + 64];
        unsigned long long Wl = __shfl_up(Wc, 1);
        unsigned long long Wr = __shfl_down(Wc, 1);
        if (wc == 0)  Wl = ~0ull;
        if (wc == 15) Wr = ~0ull;
        Ff[tid] = Wc
            & ((Wc << 1) | (Wl >> 63))
            & ((Wc << 2) | (Wl >> 62))
            & ((Wc >> 1) | (Wr << 63))
            & ((Wc >> 2) | (Wr << 62));
    }
    __syncthreads();

    // Phase 6: unpack to f32, nontemporal coalesced 16B stores
    for (int i = 0; i < PT_ROWS; i++) {
        unsigned long long wd = Ff[i * 16 + (tid >> 4)];
        int sh = (tid & 15) * 4;
        fx4 f;
        f.x = (float)((wd >> sh) & 1ull);
        f.y = (float)((wd >> (sh + 1)) & 1ull);
        f.z = (float)((wd >> (sh + 2)) & 1ull);
        f.w = (float)((wd >> (sh + 3)) & 1ull);
        fx4* dst = (fx4*)(out + (size_t)p * 1048576 + (size_t)(y0 + i) * 1024) + tid;
        __builtin_nontemporal_store(f, dst);
    }
}

extern "C" void kernel_launch(void* const* d_in, const int* in_sizes, int n_in,
                              void* d_out, int out_size, void* d_ws, size_t ws_size,
                              hipStream_t stream) {
    const float4* x4 = (const float4*)d_in[0];
    const float*  bk = (const float*)d_in[1];
    float* out = (float*)d_out;

    char* ws = (char*)d_ws;
    unsigned int*   hist = (unsigned int*)(ws + OFF_HIST);
    unsigned short* kq16 = (unsigned short*)(ws + OFF_KQ);
    const unsigned char* kqb = (const unsigned char*)(ws + OFF_KQ);

    (void)hipMemsetAsync(hist, 0, (K_STEPS + 1) * sizeof(unsigned int), stream);

    dim3 g1(1024 / R_TILE, 32);
    k_pass1<<<g1, 256, 0, stream>>>(x4, bk, hist, kq16);

    dim3 g2(1024 / PT_ROWS, 32);
    k_post<<<g2, 256, 0, stream>>>(kqb, hist, out);
}